// Round 8
// baseline (448.419 us; speedup 1.0000x reference)
//
#include <hip/hip_runtime.h>
#include <hip/hip_bf16.h>

#define B_ 32
#define N_ 1024
#define D_ 512
#define LN_EPS 1e-5f

using bf16 = __bf16;
using bf16x4 = __attribute__((ext_vector_type(4))) __bf16;
using bf16x8 = __attribute__((ext_vector_type(8))) __bf16;
using floatx4 = __attribute__((ext_vector_type(4))) float;

__device__ __forceinline__ void gld16(const bf16* gp, bf16* lp) {
  __builtin_amdgcn_global_load_lds(
      (const __attribute__((address_space(1))) void*)gp,
      (__attribute__((address_space(3))) void*)lp, 16, 0, 0);
}

// ---------------- deg (partial col sums via atomics) + Abf cast ----------------
__global__ __launch_bounds__(256) void k_deg(const float* __restrict__ A,
                                             float* __restrict__ deg,
                                             bf16* __restrict__ Abf) {
  int b = blockIdx.y;
  int i0 = blockIdx.x * 32;          // 32 rows per block
  int t = threadIdx.x;               // owns cols 4t..4t+3
  const float* p = A + (size_t)b * N_ * N_ + (size_t)i0 * N_ + t * 4;
  bf16* op = Abf + (size_t)b * N_ * N_ + (size_t)i0 * N_ + t * 4;
  float4 acc = {0.f, 0.f, 0.f, 0.f};
  #pragma unroll 4
  for (int i = 0; i < 32; ++i) {
    float4 v = *(const float4*)(p + (size_t)i * N_);
    acc.x += v.x; acc.y += v.y; acc.z += v.z; acc.w += v.w;
    bf16x4 o = {(bf16)v.x, (bf16)v.y, (bf16)v.z, (bf16)v.w};
    *(bf16x4*)(op + (size_t)i * N_) = o;
  }
  float* d = deg + b * N_ + t * 4;
  atomicAdd(d + 0, acc.x); atomicAdd(d + 1, acc.y);
  atomicAdd(d + 2, acc.z); atomicAdd(d + 3, acc.w);
}

// ------------- build Anbf = transpose(Abf)*rsqrt(deg_i)*rsqrt(deg_j)
// ------------- PLUS (z==32 plane): fp32->bf16 transposed weight casts
__global__ __launch_bounds__(256) void k_build(const bf16* __restrict__ Abf,
                                               const float* __restrict__ deg,
                                               bf16* __restrict__ Anbf,
                                               const float* __restrict__ W1,
                                               bf16* __restrict__ W1t,
                                               const float* __restrict__ W2,
                                               bf16* __restrict__ W2t) {
  __shared__ float tile[64][65];
  int t = threadIdx.x;
  if (blockIdx.z == 32) {
    int blk = blockIdx.y * 16 + blockIdx.x;   // 0..255, use 0..191
    if (blk >= 192) return;
    const float* in; bf16* outp; int R, C, c0, r0;
    if (blk < 128) {
      in = W1; outp = W1t; R = N_; C = D_;
      c0 = (blk & 7) * 64; r0 = (blk >> 3) * 64;
    } else {
      blk -= 128;
      in = W2; outp = W2t; R = D_; C = D_;
      c0 = (blk & 7) * 64; r0 = (blk >> 3) * 64;
    }
    #pragma unroll
    for (int cc = 0; cc < 4; ++cc) {
      int idx = cc * 256 + t;
      int r = idx >> 4, c4 = (idx & 15) << 2;
      const float4 v = *(const float4*)(in + (size_t)(r0 + r) * C + c0 + c4);
      tile[r][c4 + 0] = v.x; tile[r][c4 + 1] = v.y;
      tile[r][c4 + 2] = v.z; tile[r][c4 + 3] = v.w;
    }
    __syncthreads();
    #pragma unroll
    for (int cc = 0; cc < 4; ++cc) {
      int idx = cc * 256 + t;
      int c = idx >> 4, r4 = (idx & 15) << 2;
      bf16* dst = outp + (size_t)(c0 + c) * R + r0 + r4;
      #pragma unroll
      for (int e = 0; e < 4; ++e) dst[e] = (bf16)tile[r4 + e][c];
    }
    return;
  }
  __shared__ float disI[64], disJ[64];
  int b = blockIdx.z;
  int i0 = blockIdx.x * 64;   // i range (cols of A read, rows of An)
  int j0 = blockIdx.y * 64;   // j range (rows of A read)
  const bf16* Ab = Abf + (size_t)b * N_ * N_;
  bf16* Anb = Anbf + (size_t)b * N_ * N_;
  if (t < 64) {
    float v = deg[b * N_ + i0 + t];
    disI[t] = v > 0.f ? rsqrtf(v) : 0.f;
  } else if (t < 128) {
    float v = deg[b * N_ + j0 + (t - 64)];
    disJ[t - 64] = v > 0.f ? rsqrtf(v) : 0.f;
  }
  #pragma unroll
  for (int cc = 0; cc < 4; ++cc) {
    int chunk = cc * 256 + t;       // 0..1023
    int r = chunk >> 4;             // 0..63 (row j offset)
    int c4 = (chunk & 15) << 2;     // 0..60
    bf16x4 v = *(const bf16x4*)(Ab + (size_t)(j0 + r) * N_ + i0 + c4);
    tile[r][c4 + 0] = (float)v[0]; tile[r][c4 + 1] = (float)v[1];
    tile[r][c4 + 2] = (float)v[2]; tile[r][c4 + 3] = (float)v[3];
  }
  __syncthreads();
  #pragma unroll
  for (int cc = 0; cc < 4; ++cc) {
    int chunk = cc * 256 + t;
    int ii = chunk >> 4;            // 0..63 (out row offset)
    int jj4 = (chunk & 15) << 2;
    float di = disI[ii];
    bf16x4 o;
    #pragma unroll
    for (int e = 0; e < 4; ++e)
      o[e] = (bf16)(tile[jj4 + e][ii] * di * disJ[jj4 + e]);
    *(bf16x4*)(Anb + (size_t)(i0 + ii) * N_ + j0 + jj4) = o;
  }
}

// --------- MFMA GEMM: C[M,NN] = A[M,K] @ Bt[NN,K]^T ----------
// R6 two-barrier structure (validated fastest), 128x128 tile, BK=64, 4 waves,
// XOR-swizzled LDS, XCD-aware block swizzle. K/NN/grid are COMPILE-TIME:
// full K-unroll + constant-folded addressing.
template <int K, int NN, int NX, int NY, bool BIAS, bool RELU>
__global__ __launch_bounds__(256, 4) void k_gemm(
    const bf16* __restrict__ Abase, size_t strideA,
    const bf16* __restrict__ Btbase, size_t strideBt,
    bf16* __restrict__ Cbase, size_t strideC,
    const float* __restrict__ bias) {
  __shared__ bf16 sA[128 * 64];
  __shared__ bf16 sB[128 * 64];
  constexpr int nxy = NX * NY;      // blocks per batch (32)
  int L = blockIdx.z * nxy + blockIdx.y * NX + blockIdx.x;
  int b = (L & 7) + 8 * (L / (nxy * 8));
  int inner = (L >> 3) % nxy;
  int n0 = (inner % NX) * 128;
  int m0 = (inner / NX) * 128;

  const bf16* A = Abase + (size_t)b * strideA;
  const bf16* Bt = Btbase + (size_t)b * strideBt;
  int t = threadIdx.x;
  int lane = t & 63, wid = t >> 6;
  int wm = (wid >> 1) * 64, wn = (wid & 1) * 64;
  int l16 = lane & 15, q = lane >> 4;

  // staging: wave wid fills rows [wid*32, wid*32+32) of both tiles.
  // slot l of each 8-row window holds chunk (l&7)^(l>>3) of row l>>3
  int rowoff = lane >> 3;                 // 0..7
  int schunk = (lane & 7) ^ rowoff;       // swizzled source chunk
  const bf16* agp = A + (size_t)(m0 + wid * 32 + rowoff) * K + schunk * 8;
  const bf16* bgp = Bt + (size_t)(n0 + wid * 32 + rowoff) * K + schunk * 8;
  bf16* alp = &sA[wid * 2048 + lane * 8];
  bf16* blp = &sB[wid * 2048 + lane * 8];

  int xorb = l16 & 7;

  floatx4 acc[4][4];
  #pragma unroll
  for (int i = 0; i < 4; ++i)
    #pragma unroll
    for (int j = 0; j < 4; ++j) acc[i][j] = (floatx4){0.f, 0.f, 0.f, 0.f};

  #pragma unroll
  for (int kt = 0; kt < K; kt += 64) {
    #pragma unroll
    for (int s = 0; s < 4; ++s) {
      gld16(agp + (size_t)s * 8 * K + kt, alp + s * 512);
      gld16(bgp + (size_t)s * 8 * K + kt, blp + s * 512);
    }
    __syncthreads();
    #pragma unroll
    for (int h = 0; h < 2; ++h) {
      int cko = ((q + 4 * h) ^ xorb) * 8;
      bf16x8 af[4], bfr[4];
      #pragma unroll
      for (int mt = 0; mt < 4; ++mt)
        af[mt] = *(const bf16x8*)(&sA[(wm + mt * 16 + l16) * 64 + cko]);
      #pragma unroll
      for (int nt = 0; nt < 4; ++nt)
        bfr[nt] = *(const bf16x8*)(&sB[(wn + nt * 16 + l16) * 64 + cko]);
      #pragma unroll
      for (int mt = 0; mt < 4; ++mt)
        #pragma unroll
        for (int nt = 0; nt < 4; ++nt)
          acc[mt][nt] = __builtin_amdgcn_mfma_f32_16x16x32_bf16(
              af[mt], bfr[nt], acc[mt][nt], 0, 0, 0);
    }
    __syncthreads();
  }

  bf16* C = Cbase + (size_t)b * strideC;
  #pragma unroll
  for (int mt = 0; mt < 4; ++mt)
    #pragma unroll
    for (int nt = 0; nt < 4; ++nt)
      #pragma unroll
      for (int r = 0; r < 4; ++r) {
        int row = m0 + wm + mt * 16 + q * 4 + r;
        int col = n0 + wn + nt * 16 + l16;
        float v = acc[mt][nt][r];
        if (BIAS) v += bias[col];
        if (RELU) v = v > 0.f ? v : 0.f;
        C[(size_t)row * NN + col] = (bf16)v;
      }
}

// ---- LayerNorm over D + mean-pool over N (accumulate) + FUSED classifier ----
// 16 blocks per batch; the LAST block to finish (per-batch atomic counter)
// runs the tiny classifier head for that batch.
__global__ __launch_bounds__(256) void k_lnpool(
    const bf16* __restrict__ H2,
    const float* __restrict__ g, const float* __restrict__ be,
    float* __restrict__ zp_accum, int* __restrict__ cnt,
    const float* __restrict__ Wc1, const float* __restrict__ bc1,
    const float* __restrict__ g1, const float* __restrict__ t1,
    const float* __restrict__ Wc2, const float* __restrict__ bc2,
    const float* __restrict__ g2, const float* __restrict__ t2,
    const float* __restrict__ Wc3, const float* __restrict__ bc3,
    float* __restrict__ out) {
  int b = blockIdx.y;
  int r0 = blockIdx.x * 64;
  int t = threadIdx.x, lane = t & 63, w = t >> 6;
  float ge[8], bee[8];
  #pragma unroll
  for (int e = 0; e < 8; ++e) { ge[e] = g[lane * 8 + e]; bee[e] = be[lane * 8 + e]; }
  float acc[8] = {0, 0, 0, 0, 0, 0, 0, 0};
  for (int rr = 0; rr < 16; ++rr) {
    int row = r0 + w * 16 + rr;
    const bf16* p = H2 + ((size_t)b * N_ + row) * D_ + lane * 8;
    bf16x8 hv = *(const bf16x8*)p;
    float x[8];
    float s = 0.f;
    #pragma unroll
    for (int e = 0; e < 8; ++e) { x[e] = (float)hv[e]; s += x[e]; }
    #pragma unroll
    for (int off = 32; off; off >>= 1) s += __shfl_xor(s, off);
    float mu = s * (1.f / 512.f);
    float ss = 0.f;
    #pragma unroll
    for (int e = 0; e < 8; ++e) { float d = x[e] - mu; ss += d * d; }
    #pragma unroll
    for (int off = 32; off; off >>= 1) ss += __shfl_xor(ss, off);
    float rs = rsqrtf(ss * (1.f / 512.f) + LN_EPS);
    #pragma unroll
    for (int e = 0; e < 8; ++e) acc[e] += (x[e] - mu) * rs * ge[e] + bee[e];
  }
  __shared__ float part[4][512];
  #pragma unroll
  for (int e = 0; e < 8; ++e) part[w][lane * 8 + e] = acc[e];
  __syncthreads();
  #pragma unroll
  for (int k = 0; k < 2; ++k) {
    int d = t + k * 256;
    float s4 = part[0][d] + part[1][d] + part[2][d] + part[3][d];
    atomicAdd(&zp_accum[b * D_ + d], s4);
  }
  // -------- arrival counter; last block runs the classifier --------
  __threadfence();
  __shared__ int is_last;
  if (t == 0) is_last = (atomicAdd(&cnt[b], 1) == 15) ? 1 : 0;
  __syncthreads();
  if (!is_last) return;
  __threadfence();

  __shared__ float z[512];
  __shared__ float c1s[128];
  __shared__ float c2s[64];
  __shared__ float red[128];
  #pragma unroll
  for (int k = 0; k < 2; ++k) {
    int d = t + k * 256;
    float v = zp_accum[b * 512 + d] * (1.f / 1024.f);
    z[d] = v;
    out[128 + b * 512 + d] = v;   // z_pooled output region
  }
  __syncthreads();
  if (t < 128) {
    float y = bc1[t];
    for (int d = 0; d < 512; ++d) y += z[d] * Wc1[d * 128 + t];
    red[t] = y;
  }
  __syncthreads();
  if (t < 128) {
    float mu = 0.f;
    for (int k = 0; k < 128; ++k) mu += red[k];
    mu *= (1.f / 128.f);
    float var = 0.f;
    for (int k = 0; k < 128; ++k) { float dd = red[k] - mu; var += dd * dd; }
    var *= (1.f / 128.f);
    float c = (red[t] - mu) * rsqrtf(var + LN_EPS) * g1[t] + t1[t];
    c1s[t] = c > 0.f ? c : 0.f;
  }
  __syncthreads();
  if (t < 64) {
    float y2 = bc2[t];
    for (int k = 0; k < 128; ++k) y2 += c1s[k] * Wc2[k * 64 + t];
    red[t] = y2;
  }
  __syncthreads();
  if (t < 64) {
    float mu2 = 0.f;
    for (int k = 0; k < 64; ++k) mu2 += red[k];
    mu2 *= (1.f / 64.f);
    float v2 = 0.f;
    for (int k = 0; k < 64; ++k) { float dd = red[k] - mu2; v2 += dd * dd; }
    v2 *= (1.f / 64.f);
    float cc = (red[t] - mu2) * rsqrtf(v2 + LN_EPS) * g2[t] + t2[t];
    c2s[t] = cc > 0.f ? cc : 0.f;
  }
  __syncthreads();
  if (t < 4) {
    float y3 = bc3[t];
    for (int k = 0; k < 64; ++k) y3 += c2s[k] * Wc3[k * 4 + t];
    out[b * 4 + t] = y3;
  }
}

extern "C" void kernel_launch(void* const* d_in, const int* in_sizes, int n_in,
                              void* d_out, int out_size, void* d_ws, size_t ws_size,
                              hipStream_t stream) {
  const float* A   = (const float*)d_in[0];
  const float* W1  = (const float*)d_in[1];
  const float* b1  = (const float*)d_in[2];
  const float* W2  = (const float*)d_in[3];
  const float* b2  = (const float*)d_in[4];
  const float* lng = (const float*)d_in[5];
  const float* lnb = (const float*)d_in[6];
  const float* Wc1 = (const float*)d_in[7];
  const float* bc1 = (const float*)d_in[8];
  const float* g1  = (const float*)d_in[9];
  const float* t1  = (const float*)d_in[10];
  const float* Wc2 = (const float*)d_in[11];
  const float* bc2 = (const float*)d_in[12];
  const float* g2  = (const float*)d_in[13];
  const float* t2  = (const float*)d_in[14];
  const float* Wc3 = (const float*)d_in[15];
  const float* bc3 = (const float*)d_in[16];
  float* out = (float*)d_out;

  char* ws = (char*)d_ws;
  size_t off = 0;
  auto alloc = [&](size_t bytes) {
    char* p = ws + off;
    off += (bytes + 255) & ~(size_t)255;
    return p;
  };
  // deg, zp, cnt adjacent -> one clearing memset
  float* deg  = (float*)alloc((size_t)B_ * N_ * 4);          // raw col sums
  float* zp   = (float*)alloc((size_t)B_ * D_ * 4);          // pooled accum
  int*  cnt   = (int*)alloc(B_ * 4);                         // arrival counters
  size_t clear_bytes = off;
  bf16* Anbf  = (bf16*)alloc((size_t)B_ * N_ * N_ * 2);      // 64 MB
  bf16* W1t   = (bf16*)alloc((size_t)D_ * N_ * 2);           // [512 x 1024]
  bf16* W2t   = (bf16*)alloc((size_t)D_ * D_ * 2);           // [512 x 512]
  bf16* T12t  = (bf16*)alloc((size_t)B_ * D_ * N_ * 2);      // T1t then T2t
  bf16* H1    = (bf16*)alloc((size_t)B_ * N_ * D_ * 2);      // [b][1024][512]
  bf16* Abf   = (bf16*)alloc((size_t)B_ * N_ * N_ * 2);      // later reused as H2
  bf16* H2    = Abf;                                          // Abf dead after GEMM1

  hipMemsetAsync(deg, 0, clear_bytes, stream);

  k_deg<<<dim3(32, B_), 256, 0, stream>>>(A, deg, Abf);
  // z=0..31: An build; z=32: weight transposes
  k_build<<<dim3(16, 16, 33), 256, 0, stream>>>(Abf, deg, Anbf, W1, W1t, W2, W2t);

  // G1: T1t[512,1024] = W1t[512,1024] @ Abf[1024,1024]^T   (T1 = A @ W1, transposed)
  k_gemm<1024, 1024, 8, 4, false, false><<<dim3(8, 4, B_), 256, 0, stream>>>(
      W1t, 0, Abf, (size_t)N_ * N_, T12t, (size_t)D_ * N_, nullptr);
  // G2: H1[1024,512] = relu(An[1024,1024] @ T1t[512,1024]^T + b1)
  k_gemm<1024, 512, 4, 8, true, true><<<dim3(4, 8, B_), 256, 0, stream>>>(
      Anbf, (size_t)N_ * N_, T12t, (size_t)D_ * N_, H1, (size_t)N_ * D_, b1);
  // G3: T2t[512,1024] = W2t[512,512] @ H1[1024,512]^T      (T2 = H1 @ W2, transposed)
  k_gemm<512, 1024, 8, 4, false, false><<<dim3(8, 4, B_), 256, 0, stream>>>(
      W2t, 0, H1, (size_t)N_ * D_, T12t, (size_t)D_ * N_, nullptr);
  // G4: H2[1024,512] = An[1024,1024] @ T2t[512,1024]^T + b2
  k_gemm<1024, 512, 4, 8, true, false><<<dim3(4, 8, B_), 256, 0, stream>>>(
      Anbf, (size_t)N_ * N_, T12t, (size_t)D_ * N_, H2, (size_t)N_ * D_, b2);

  k_lnpool<<<dim3(16, B_), 256, 0, stream>>>(
      H2, lng, lnb, zp, cnt,
      Wc1, bc1, g1, t1, Wc2, bc2, g2, t2, Wc3, bc3, out);
}

// Round 9
// 416.982 us; speedup vs baseline: 1.0754x; 1.0754x over previous
//
#include <hip/hip_runtime.h>
#include <hip/hip_bf16.h>

#define B_ 32
#define N_ 1024
#define D_ 512
#define LN_EPS 1e-5f

using bf16 = __bf16;
using bf16x4 = __attribute__((ext_vector_type(4))) __bf16;
using bf16x8 = __attribute__((ext_vector_type(8))) __bf16;
using floatx4 = __attribute__((ext_vector_type(4))) float;

__device__ __forceinline__ void gld16(const bf16* gp, bf16* lp) {
  __builtin_amdgcn_global_load_lds(
      (const __attribute__((address_space(1))) void*)gp,
      (__attribute__((address_space(3))) void*)lp, 16, 0, 0);
}

// ---------------- deg (partial col sums via atomics) + Abf cast ----------------
__global__ __launch_bounds__(256) void k_deg(const float* __restrict__ A,
                                             float* __restrict__ deg,
                                             bf16* __restrict__ Abf) {
  int b = blockIdx.y;
  int i0 = blockIdx.x * 32;          // 32 rows per block
  int t = threadIdx.x;               // owns cols 4t..4t+3
  const float* p = A + (size_t)b * N_ * N_ + (size_t)i0 * N_ + t * 4;
  bf16* op = Abf + (size_t)b * N_ * N_ + (size_t)i0 * N_ + t * 4;
  float4 acc = {0.f, 0.f, 0.f, 0.f};
  #pragma unroll 4
  for (int i = 0; i < 32; ++i) {
    float4 v = *(const float4*)(p + (size_t)i * N_);
    acc.x += v.x; acc.y += v.y; acc.z += v.z; acc.w += v.w;
    bf16x4 o = {(bf16)v.x, (bf16)v.y, (bf16)v.z, (bf16)v.w};
    *(bf16x4*)(op + (size_t)i * N_) = o;
  }
  float* d = deg + b * N_ + t * 4;
  atomicAdd(d + 0, acc.x); atomicAdd(d + 1, acc.y);
  atomicAdd(d + 2, acc.z); atomicAdd(d + 3, acc.w);
}

// ------------- build Anbf = transpose(Abf) * rsqrt(deg_i) * rsqrt(deg_j) -------------
__global__ __launch_bounds__(256) void k_build(const bf16* __restrict__ Abf,
                                               const float* __restrict__ deg,
                                               bf16* __restrict__ Anbf) {
  __shared__ float tile[64][65];
  __shared__ float disI[64], disJ[64];
  int b = blockIdx.z;
  int i0 = blockIdx.x * 64;   // i range (cols of A read, rows of An)
  int j0 = blockIdx.y * 64;   // j range (rows of A read)
  int t = threadIdx.x;
  const bf16* Ab = Abf + (size_t)b * N_ * N_;
  bf16* Anb = Anbf + (size_t)b * N_ * N_;
  if (t < 64) {
    float v = deg[b * N_ + i0 + t];
    disI[t] = v > 0.f ? rsqrtf(v) : 0.f;
  } else if (t < 128) {
    float v = deg[b * N_ + j0 + (t - 64)];
    disJ[t - 64] = v > 0.f ? rsqrtf(v) : 0.f;
  }
  #pragma unroll
  for (int cc = 0; cc < 4; ++cc) {
    int chunk = cc * 256 + t;       // 0..1023
    int r = chunk >> 4;             // 0..63 (row j offset)
    int c4 = (chunk & 15) << 2;     // 0..60
    bf16x4 v = *(const bf16x4*)(Ab + (size_t)(j0 + r) * N_ + i0 + c4);
    tile[r][c4 + 0] = (float)v[0]; tile[r][c4 + 1] = (float)v[1];
    tile[r][c4 + 2] = (float)v[2]; tile[r][c4 + 3] = (float)v[3];
  }
  __syncthreads();
  #pragma unroll
  for (int cc = 0; cc < 4; ++cc) {
    int chunk = cc * 256 + t;
    int ii = chunk >> 4;            // 0..63 (out row offset)
    int jj4 = (chunk & 15) << 2;
    float di = disI[ii];
    bf16x4 o;
    #pragma unroll
    for (int e = 0; e < 4; ++e)
      o[e] = (bf16)(tile[jj4 + e][ii] * di * disJ[jj4 + e]);
    *(bf16x4*)(Anb + (size_t)(i0 + ii) * N_ + j0 + jj4) = o;
  }
}

// -------- fp32 -> bf16 transposed cast for BOTH weights, one dispatch --------
__global__ __launch_bounds__(256) void k_transpose(const float* __restrict__ W1,
                                                   bf16* __restrict__ W1t,
                                                   const float* __restrict__ W2,
                                                   bf16* __restrict__ W2t) {
  __shared__ float tile[64][65];
  int blk = blockIdx.x;
  const float* in; bf16* outp; int R, C, c0, r0;
  if (blk < 128) {
    in = W1; outp = W1t; R = N_; C = D_;
    c0 = (blk & 7) * 64; r0 = (blk >> 3) * 64;
  } else {
    blk -= 128;
    in = W2; outp = W2t; R = D_; C = D_;
    c0 = (blk & 7) * 64; r0 = (blk >> 3) * 64;
  }
  int t = threadIdx.x;
  #pragma unroll
  for (int cc = 0; cc < 4; ++cc) {
    int idx = cc * 256 + t;
    int r = idx >> 4, c4 = (idx & 15) << 2;
    const float4 v = *(const float4*)(in + (size_t)(r0 + r) * C + c0 + c4);
    tile[r][c4 + 0] = v.x; tile[r][c4 + 1] = v.y;
    tile[r][c4 + 2] = v.z; tile[r][c4 + 3] = v.w;
  }
  __syncthreads();
  #pragma unroll
  for (int cc = 0; cc < 4; ++cc) {
    int idx = cc * 256 + t;
    int c = idx >> 4, r4 = (idx & 15) << 2;
    bf16* dst = outp + (size_t)(c0 + c) * R + r0 + r4;
    #pragma unroll
    for (int e = 0; e < 4; ++e) dst[e] = (bf16)tile[r4 + e][c];
  }
}

// --------- MFMA GEMM: C[M,Nn] = A[M,K] @ Bt[Nn,K]^T ----------
// 128x256 block tile, 4 waves each 64x128 (cuts LDS-read bytes/FLOP 25% vs
// 64x64), BK=64, two-barrier K-loop (validated fastest structure),
// XOR-swizzled LDS, XCD-aware block swizzle. 48KB LDS, 2 blocks/CU.
template <bool BIAS, bool RELU>
__global__ __launch_bounds__(256, 2) void k_gemm(
    const bf16* __restrict__ Abase, size_t strideA,
    const bf16* __restrict__ Btbase, size_t strideBt,
    bf16* __restrict__ Cbase, size_t strideC,
    const float* __restrict__ bias, int Nn, int K) {
  __shared__ bf16 sA[128 * 64];
  __shared__ bf16 sB[256 * 64];
  // XCD swizzle: batch b's blocks all land on XCD b%8
  int nxy = gridDim.x * gridDim.y;            // blocks per batch (16 here)
  int L = blockIdx.z * nxy + blockIdx.y * gridDim.x + blockIdx.x;
  int b = (L & 7) + 8 * (L / (nxy * 8));
  int inner = (L >> 3) % nxy;
  int n0 = (inner % gridDim.x) * 256;
  int m0 = (inner / gridDim.x) * 128;

  const bf16* A = Abase + (size_t)b * strideA;
  const bf16* Bt = Btbase + (size_t)b * strideBt;
  int t = threadIdx.x;
  int lane = t & 63, wid = t >> 6;
  int wm = (wid >> 1) * 64, wn = (wid & 1) * 128;
  int l16 = lane & 15, q = lane >> 4;

  // staging: wave wid fills A rows [wid*32, wid*32+32) and B rows
  // [wid*64, wid*64+64). slot l of each 8-row window holds chunk
  // (l&7)^(l>>3) of row l>>3 (XOR swizzle, rows are 64 bf16 = 128B).
  int rowoff = lane >> 3;                 // 0..7
  int schunk = (lane & 7) ^ rowoff;       // swizzled source chunk
  const bf16* agp = A + (size_t)(m0 + wid * 32 + rowoff) * K + schunk * 8;
  const bf16* bgp = Bt + (size_t)(n0 + wid * 64 + rowoff) * K + schunk * 8;
  bf16* alp = &sA[wid * 2048 + lane * 8];
  bf16* blp = &sB[wid * 4096 + lane * 8];

  int xorb = l16 & 7;

  floatx4 acc[4][8];
  #pragma unroll
  for (int i = 0; i < 4; ++i)
    #pragma unroll
    for (int j = 0; j < 8; ++j) acc[i][j] = (floatx4){0.f, 0.f, 0.f, 0.f};

  for (int kt = 0; kt < K; kt += 64) {
    #pragma unroll
    for (int s = 0; s < 4; ++s)
      gld16(agp + (size_t)s * 8 * K + kt, alp + s * 512);
    #pragma unroll
    for (int s = 0; s < 8; ++s)
      gld16(bgp + (size_t)s * 8 * K + kt, blp + s * 512);
    __syncthreads();
    #pragma unroll
    for (int h = 0; h < 2; ++h) {
      int cko = ((q + 4 * h) ^ xorb) * 8;
      bf16x8 af[4], bfr[8];
      #pragma unroll
      for (int mt = 0; mt < 4; ++mt)
        af[mt] = *(const bf16x8*)(&sA[(wm + mt * 16 + l16) * 64 + cko]);
      #pragma unroll
      for (int nt = 0; nt < 8; ++nt)
        bfr[nt] = *(const bf16x8*)(&sB[(wn + nt * 16 + l16) * 64 + cko]);
      #pragma unroll
      for (int mt = 0; mt < 4; ++mt)
        #pragma unroll
        for (int nt = 0; nt < 8; ++nt)
          acc[mt][nt] = __builtin_amdgcn_mfma_f32_16x16x32_bf16(
              af[mt], bfr[nt], acc[mt][nt], 0, 0, 0);
    }
    __syncthreads();
  }

  bf16* C = Cbase + (size_t)b * strideC;
  #pragma unroll
  for (int mt = 0; mt < 4; ++mt)
    #pragma unroll
    for (int nt = 0; nt < 8; ++nt)
      #pragma unroll
      for (int r = 0; r < 4; ++r) {
        int row = m0 + wm + mt * 16 + q * 4 + r;
        int col = n0 + wn + nt * 16 + l16;
        float v = acc[mt][nt][r];
        if (BIAS) v += bias[col];
        if (RELU) v = v > 0.f ? v : 0.f;
        C[(size_t)row * Nn + col] = (bf16)v;
      }
}

// ---------------- LayerNorm over D + mean-pool over N (accumulate) ----------------
__global__ __launch_bounds__(256) void k_lnpool(const bf16* __restrict__ H2,
                                                const float* __restrict__ g,
                                                const float* __restrict__ be,
                                                float* __restrict__ zp_accum) {
  int b = blockIdx.y;
  int r0 = blockIdx.x * 64;
  int t = threadIdx.x, lane = t & 63, w = t >> 6;
  float ge[8], bee[8];
  #pragma unroll
  for (int e = 0; e < 8; ++e) { ge[e] = g[lane * 8 + e]; bee[e] = be[lane * 8 + e]; }
  float acc[8] = {0, 0, 0, 0, 0, 0, 0, 0};
  for (int rr = 0; rr < 16; ++rr) {
    int row = r0 + w * 16 + rr;
    const bf16* p = H2 + ((size_t)b * N_ + row) * D_ + lane * 8;
    bf16x8 hv = *(const bf16x8*)p;
    float x[8];
    float s = 0.f;
    #pragma unroll
    for (int e = 0; e < 8; ++e) { x[e] = (float)hv[e]; s += x[e]; }
    #pragma unroll
    for (int off = 32; off; off >>= 1) s += __shfl_xor(s, off);
    float mu = s * (1.f / 512.f);
    float ss = 0.f;
    #pragma unroll
    for (int e = 0; e < 8; ++e) { float d = x[e] - mu; ss += d * d; }
    #pragma unroll
    for (int off = 32; off; off >>= 1) ss += __shfl_xor(ss, off);
    float rs = rsqrtf(ss * (1.f / 512.f) + LN_EPS);
    #pragma unroll
    for (int e = 0; e < 8; ++e) acc[e] += (x[e] - mu) * rs * ge[e] + bee[e];
  }
  __shared__ float part[4][512];
  #pragma unroll
  for (int e = 0; e < 8; ++e) part[w][lane * 8 + e] = acc[e];
  __syncthreads();
  #pragma unroll
  for (int k = 0; k < 2; ++k) {
    int d = t + k * 256;
    float s4 = part[0][d] + part[1][d] + part[2][d] + part[3][d];
    atomicAdd(&zp_accum[b * D_ + d], s4);
  }
}

// ---------------- classifier head (tiny) ----------------
__global__ __launch_bounds__(128) void k_cls(
    const float* __restrict__ zp_accum,
    const float* __restrict__ Wc1, const float* __restrict__ bc1,
    const float* __restrict__ g1, const float* __restrict__ t1,
    const float* __restrict__ Wc2, const float* __restrict__ bc2,
    const float* __restrict__ g2, const float* __restrict__ t2,
    const float* __restrict__ Wc3, const float* __restrict__ bc3,
    float* __restrict__ out) {
  __shared__ float z[512];
  __shared__ float c1s[128];
  __shared__ float c2s[64];
  __shared__ float red[128];
  int b = blockIdx.x, t = threadIdx.x;
  #pragma unroll
  for (int k = 0; k < 4; ++k) {
    int d = t + k * 128;
    float v = zp_accum[b * 512 + d] * (1.f / 1024.f);
    z[d] = v;
    out[128 + b * 512 + d] = v;   // z_pooled output region
  }
  __syncthreads();
  float y = bc1[t];
  for (int d = 0; d < 512; ++d) y += z[d] * Wc1[d * 128 + t];
  red[t] = y;
  __syncthreads();
  float mu = 0.f;
  for (int k = 0; k < 128; ++k) mu += red[k];
  mu *= (1.f / 128.f);
  float var = 0.f;
  for (int k = 0; k < 128; ++k) { float dd = red[k] - mu; var += dd * dd; }
  var *= (1.f / 128.f);
  float c = (y - mu) * rsqrtf(var + LN_EPS) * g1[t] + t1[t];
  c1s[t] = c > 0.f ? c : 0.f;
  __syncthreads();
  if (t < 64) {
    float y2 = bc2[t];
    for (int k = 0; k < 128; ++k) y2 += c1s[k] * Wc2[k * 64 + t];
    red[t] = y2;
  }
  __syncthreads();
  if (t < 64) {
    float mu2 = 0.f;
    for (int k = 0; k < 64; ++k) mu2 += red[k];
    mu2 *= (1.f / 64.f);
    float v2 = 0.f;
    for (int k = 0; k < 64; ++k) { float dd = red[k] - mu2; v2 += dd * dd; }
    v2 *= (1.f / 64.f);
    float cc = (red[t] - mu2) * rsqrtf(v2 + LN_EPS) * g2[t] + t2[t];
    c2s[t] = cc > 0.f ? cc : 0.f;
  }
  __syncthreads();
  if (t < 4) {
    float y3 = bc3[t];
    for (int k = 0; k < 64; ++k) y3 += c2s[k] * Wc3[k * 4 + t];
    out[b * 4 + t] = y3;
  }
}

extern "C" void kernel_launch(void* const* d_in, const int* in_sizes, int n_in,
                              void* d_out, int out_size, void* d_ws, size_t ws_size,
                              hipStream_t stream) {
  const float* A   = (const float*)d_in[0];
  const float* W1  = (const float*)d_in[1];
  const float* b1  = (const float*)d_in[2];
  const float* W2  = (const float*)d_in[3];
  const float* b2  = (const float*)d_in[4];
  const float* lng = (const float*)d_in[5];
  const float* lnb = (const float*)d_in[6];
  const float* Wc1 = (const float*)d_in[7];
  const float* bc1 = (const float*)d_in[8];
  const float* g1  = (const float*)d_in[9];
  const float* t1  = (const float*)d_in[10];
  const float* Wc2 = (const float*)d_in[11];
  const float* bc2 = (const float*)d_in[12];
  const float* g2  = (const float*)d_in[13];
  const float* t2  = (const float*)d_in[14];
  const float* Wc3 = (const float*)d_in[15];
  const float* bc3 = (const float*)d_in[16];
  float* out = (float*)d_out;

  char* ws = (char*)d_ws;
  size_t off = 0;
  auto alloc = [&](size_t bytes) {
    char* p = ws + off;
    off += (bytes + 255) & ~(size_t)255;
    return p;
  };
  // deg and zp adjacent -> one clearing memset
  float* deg  = (float*)alloc((size_t)B_ * N_ * 4);          // raw col sums
  float* zp   = (float*)alloc((size_t)B_ * D_ * 4);          // pooled accum
  bf16* Anbf  = (bf16*)alloc((size_t)B_ * N_ * N_ * 2);      // 64 MB
  bf16* W1t   = (bf16*)alloc((size_t)D_ * N_ * 2);           // [512 x 1024]
  bf16* W2t   = (bf16*)alloc((size_t)D_ * D_ * 2);           // [512 x 512]
  bf16* T12t  = (bf16*)alloc((size_t)B_ * D_ * N_ * 2);      // T1t then T2t
  bf16* H1    = (bf16*)alloc((size_t)B_ * N_ * D_ * 2);      // [b][1024][512]
  bf16* Abf   = (bf16*)alloc((size_t)B_ * N_ * N_ * 2);      // later reused as H2
  bf16* H2    = Abf;                                          // Abf dead after GEMM1

  hipMemsetAsync(deg, 0, (size_t)B_ * N_ * 4 + (size_t)B_ * D_ * 4 + 256, stream);

  k_deg<<<dim3(32, B_), 256, 0, stream>>>(A, deg, Abf);
  k_build<<<dim3(16, 16, B_), 256, 0, stream>>>(Abf, deg, Anbf);
  k_transpose<<<192, 256, 0, stream>>>(W1, W1t, W2, W2t);

  // G1: T1t[512,1024] = W1t[512,1024] @ Abf[1024,1024]^T   (T1 = A @ W1, transposed)
  k_gemm<false, false><<<dim3(4, 4, B_), 256, 0, stream>>>(
      W1t, 0, Abf, (size_t)N_ * N_, T12t, (size_t)D_ * N_, nullptr, N_, N_);
  // G2: H1[1024,512] = relu(An[1024,1024] @ T1t[512,1024]^T + b1)
  k_gemm<true, true><<<dim3(2, 8, B_), 256, 0, stream>>>(
      Anbf, (size_t)N_ * N_, T12t, (size_t)D_ * N_, H1, (size_t)N_ * D_, b1, D_, N_);
  // G3: T2t[512,1024] = W2t[512,512] @ H1[1024,512]^T      (T2 = H1 @ W2, transposed)
  k_gemm<false, false><<<dim3(4, 4, B_), 256, 0, stream>>>(
      W2t, 0, H1, (size_t)N_ * D_, T12t, (size_t)D_ * N_, nullptr, N_, D_);
  // G4: H2[1024,512] = An[1024,1024] @ T2t[512,1024]^T + b2
  k_gemm<true, false><<<dim3(2, 8, B_), 256, 0, stream>>>(
      Anbf, (size_t)N_ * N_, T12t, (size_t)D_ * N_, H2, (size_t)N_ * D_, b2, D_, N_);

  k_lnpool<<<dim3(16, B_), 256, 0, stream>>>(H2, lng, lnb, zp);
  k_cls<<<B_, 128, 0, stream>>>(zp, Wc1, bc1, g1, t1, Wc2, bc2, g2, t2, Wc3, bc3, out);
}